// Round 9
// baseline (316.467 us; speedup 1.0000x reference)
//
#include <hip/hip_runtime.h>
#include <hip/hip_bf16.h>
#include <math.h>

#define BB 32
#define SS 4096
#define HH 256

typedef __bf16 bf16x8 __attribute__((ext_vector_type(8)));
typedef float f32x4 __attribute__((ext_vector_type(4)));

#define GLOBAL_AS __attribute__((address_space(1)))
#define LDS_AS    __attribute__((address_space(3)))

__device__ inline bf16x8 cvt8(const float4& x, const float4& y) {
    union { __hip_bfloat162 p[4]; bf16x8 v; } u;
    u.p[0] = __float22bfloat162_rn(make_float2(x.x, x.y));
    u.p[1] = __float22bfloat162_rn(make_float2(x.z, x.w));
    u.p[2] = __float22bfloat162_rn(make_float2(y.x, y.y));
    u.p[3] = __float22bfloat162_rn(make_float2(y.z, y.w));
    return u.v;
}

// tanh via exp path: ~6 VALU ops. |rel err| ~1e-7.
__device__ inline float fast_tanh(float x) {
    float xc = fminf(fmaxf(x, -10.f), 10.f);
    float e  = __expf(2.f * xc);
    return (e - 1.f) * __builtin_amdgcn_rcpf(e + 1.f);
}

// ---------------------------------------------------------------------------
// Prep (fused): blocks 0..255 swizzle W2 -> bf16 MFMA-B order;
// blocks 256..287: qq[b][h] = hidden[b]@W1[:,h] + W1_b[h] + W2_b[h];
// block 288: M = sum_h |V_w[h]| (fixed softmax shift; V_b cancels).
// w2sw[((kc*16+nt)*64+lane)*8+j] = W2[kc*32+(lane>>4)*8+j][nt*16+(lane&15)]
// ---------------------------------------------------------------------------
__global__ void prep_kernel(const float* __restrict__ W2_w,
                            ushort* __restrict__ w2sw,
                            const float* __restrict__ hidden,
                            const float* __restrict__ W1_w,
                            const float* __restrict__ W1_b,
                            const float* __restrict__ W2_b,
                            const float* __restrict__ V_w,
                            float* __restrict__ qq,
                            float* __restrict__ Mout) {
    __shared__ float red[HH];
    const int t = threadIdx.x;
    if (blockIdx.x < 256) {
        const int i = blockIdx.x * 256 + t;
        const int j    = i & 7;
        const int lane = (i >> 3) & 63;
        const int nt   = (i >> 9) & 15;
        const int kc   = i >> 13;
        const int k = kc * 32 + ((lane >> 4) & 3) * 8 + j;
        const int n = nt * 16 + (lane & 15);
        __hip_bfloat16 h = __float2bfloat16(W2_w[k * HH + n]);
        w2sw[i] = *(ushort*)&h;
    } else if (blockIdx.x < 256 + BB) {
        const int b = blockIdx.x - 256;
        red[t] = hidden[b * HH + t];
        __syncthreads();
        float acc = 0.f;
#pragma unroll 16
        for (int k = 0; k < HH; ++k)
            acc = fmaf(red[k], W1_w[k * HH + t], acc);
        qq[b * HH + t] = acc + W1_b[t] + W2_b[t];
    } else {
        red[t] = fabsf(V_w[t]);
        __syncthreads();
        for (int off = 128; off > 0; off >>= 1) {
            if (t < off) red[t] += red[t + off];
            __syncthreads();
        }
        if (t == 0) Mout[0] = red[0];
    }
}

// ---------------------------------------------------------------------------
// Fused score + partial-context. grid (8, BB), block 512 = 8 waves
// (mw = wave&1 over 32-row halves, nh = wave>>2.. see below), 8 tiles/block.
// All A traffic via global_load_lds (no dest VGPR -> compiler CANNOT sink it;
// R5-R8 showed register loads always collapse to per-use latency). A-tile
// 64x256 fp32 = 64 KB, double-buffered; next tile staged under the current
// epilogue. B (W2) = 128 persistent VGPRs loaded once per block (invariant
// across tiles -> allocator must keep them live). ctx reads the LDS A-tile.
// A-tile is XOR-bank-swizzled (chunk c^=(row&7)) on the DMA's global-source
// side: conflict-free MFMA reads AND ctx column reads.
// ---------------------------------------------------------------------------
__global__ __launch_bounds__(512, 2)
void score_ctx_kernel(const float* __restrict__ enc,
                      const ushort* __restrict__ w2sw,
                      const float* __restrict__ qq,
                      const float* __restrict__ V_w,
                      const float* __restrict__ Mptr,
                      float* __restrict__ wtilde_out,
                      float* __restrict__ part) {
    __shared__ float Abuf[2][16384];   // 2 x 64 KB, swizzled
    __shared__ float sc_part[4][64];
    __shared__ float sc_w[64];
    __shared__ float accl2[2][HH];

    const int t    = threadIdx.x;
    const int wave = t >> 6;
    const int lane = t & 63;
    const int mw   = wave & 1;          // 32-row half
    const int nh   = wave >> 1;         // 0..3: 64-col slice
    const int l15  = lane & 15;
    const int quad = lane >> 4;
    const int b    = blockIdx.y;
    const int seg  = blockIdx.x;        // tiles c = seg*8 + ii

    // ---- B: persistent registers, loaded once (invariant across 8 tiles)
    const bf16x8* bgl = (const bf16x8*)w2sw;
    bf16x8 bq[8][4];
#pragma unroll
    for (int kc = 0; kc < 8; ++kc)
#pragma unroll
        for (int nt = 0; nt < 4; ++nt)
            bq[kc][nt] = bgl[kc * 1024 + (nh * 4 + nt) * 64 + lane];

    // per-wave epilogue constants
    const float Mv = Mptr[0];
    float qv[4], vv[4];
#pragma unroll
    for (int nt = 0; nt < 4; ++nt) {
        const int n = (nh * 4 + nt) * 16 + l15;
        qv[nt] = qq[b * HH + n];
        vv[nt] = V_w[n];
    }

    // ---- A staging: tile c -> Abuf[bufi], 16B chunk (r, c') <- global (r, c)
    // with c' = (c & 56) | ((c & 7) ^ (r & 7)); slot s = i*512 + t.
    auto stage = [&](int c, int bufi) {
        const char* gbase = (const char*)(enc + ((size_t)(b * SS + c * 64)) * HH);
        char* lbase = (char*)&Abuf[bufi][0];
#pragma unroll
        for (int i = 0; i < 8; ++i) {
            const int s  = i * 512 + t;
            const int r  = s >> 6;
            const int cp = s & 63;
            const int g  = r * 64 + ((cp & 56) | ((cp & 7) ^ (r & 7)));
            __builtin_amdgcn_global_load_lds(
                (const GLOBAL_AS void*)(gbase + (size_t)g * 16),
                (LDS_AS void*)(lbase + i * 8192 + wave * 1024), 16, 0, 0);
        }
    };

    stage(seg * 8, 0);

    for (int ii = 0; ii < 8; ++ii) {
        const int cur = ii & 1;
        const int c   = seg * 8 + ii;
        const int s0  = c * 64;
        __syncthreads();   // staging of `cur` drained; prev ctx done reading

        // ---- K-loop: pure LDS reads + MFMA (no global ops)
        f32x4 acc[2][4];
#pragma unroll
        for (int mt = 0; mt < 2; ++mt)
#pragma unroll
            for (int nt = 0; nt < 4; ++nt) acc[mt][nt] = (f32x4)0.f;

#pragma unroll
        for (int kc = 0; kc < 8; ++kc) {
            bf16x8 af[2];
#pragma unroll
            for (int mt = 0; mt < 2; ++mt) {
                const int R  = mw * 32 + mt * 16 + l15;
                const int c0 = kc * 8 + quad * 2;      // 16B chunk, even
                const int x0 = (c0 & 56) | ((c0 & 7) ^ (R & 7));
                const int x1 = (c0 & 56) | (((c0 + 1) & 7) ^ (R & 7));
                const float4 x = *(const float4*)&Abuf[cur][(R * 64 + x0) * 4];
                const float4 y = *(const float4*)&Abuf[cur][(R * 64 + x1) * 4];
                af[mt] = cvt8(x, y);
            }
#pragma unroll
            for (int nt = 0; nt < 4; ++nt) {
                acc[0][nt] = __builtin_amdgcn_mfma_f32_16x16x32_bf16(
                    af[0], bq[kc][nt], acc[0][nt], 0, 0, 0);
                acc[1][nt] = __builtin_amdgcn_mfma_f32_16x16x32_bf16(
                    af[1], bq[kc][nt], acc[1][nt], 0, 0, 0);
            }
        }

        // issue next tile's staging now; latency hides under the epilogue
        if (ii < 7) stage(c + 1, cur ^ 1);

        // ---- epilogue: V-dot partial over this wave's 64 n-cols
        float p[2][4] = {{0.f, 0.f, 0.f, 0.f}, {0.f, 0.f, 0.f, 0.f}};
#pragma unroll
        for (int nt = 0; nt < 4; ++nt)
#pragma unroll
            for (int mt = 0; mt < 2; ++mt)
#pragma unroll
                for (int r = 0; r < 4; ++r)
                    p[mt][r] = fmaf(vv[nt], fast_tanh(qv[nt] + acc[mt][nt][r]),
                                    p[mt][r]);
#pragma unroll
        for (int off = 1; off < 16; off <<= 1)
#pragma unroll
            for (int mt = 0; mt < 2; ++mt)
#pragma unroll
                for (int r = 0; r < 4; ++r)
                    p[mt][r] += __shfl_xor(p[mt][r], off);

        if (l15 == 0) {
#pragma unroll
            for (int mt = 0; mt < 2; ++mt)
                *(float4*)&sc_part[nh][mw * 32 + mt * 16 + quad * 4] =
                    make_float4(p[mt][0], p[mt][1], p[mt][2], p[mt][3]);
        }
        __syncthreads();
        if (t < 64) {
            const float s = sc_part[0][t] + sc_part[1][t] +
                            sc_part[2][t] + sc_part[3][t];
            const float wt = __expf(s - Mv);
            sc_w[t] = wt;
            wtilde_out[b * SS + s0 + t] = wt;
        }
        __syncthreads();

        // ---- ctx partial from the LDS A-tile (no global reads)
        {
            const int h  = t & 255;
            const int jg = t >> 8;               // 0/1
            const int ch = h >> 2, hr = h & 3;
            float a = 0.f;
#pragma unroll
            for (int jj = 0; jj < 32; ++jj) {
                const int j  = jj * 2 + jg;
                const int cs = (ch & 56) | ((ch & 7) ^ (j & 7));
                a = fmaf(sc_w[j], Abuf[cur][(j * 64 + cs) * 4 + hr], a);
            }
            accl2[jg][h] = a;
        }
        __syncthreads();
        if (t < HH)
            part[((size_t)(b * 64 + c)) * HH + t] = accl2[0][t] + accl2[1][t];
    }
}

// ---------------------------------------------------------------------------
// Finish: grid (BB), block 256. l = sum_s wtilde (read from d_out),
// weights normalized in place; ctx = (sum_c part)/l.
// ---------------------------------------------------------------------------
__global__ __launch_bounds__(256)
void finish_kernel(const float* __restrict__ part,
                   float* __restrict__ weights_out,
                   float* __restrict__ ctx_out) {
    __shared__ float red[256];
    __shared__ float linv_s;
    const int b = blockIdx.x;
    const int t = threadIdx.x;

    float4* wo4 = (float4*)(weights_out + (size_t)b * SS);
    float4 vals[4];
    float l = 0.f;
#pragma unroll
    for (int i = 0; i < 4; ++i) {
        vals[i] = wo4[i * 256 + t];
        l += vals[i].x + vals[i].y + vals[i].z + vals[i].w;
    }
    red[t] = l;
    __syncthreads();
    for (int off = 128; off > 0; off >>= 1) {
        if (t < off) red[t] += red[t + off];
        __syncthreads();
    }
    if (t == 0) linv_s = 1.f / red[0];
    __syncthreads();
    const float linv = linv_s;

#pragma unroll
    for (int i = 0; i < 4; ++i) {
        const float4 v = vals[i];
        wo4[i * 256 + t] =
            make_float4(v.x * linv, v.y * linv, v.z * linv, v.w * linv);
    }

    float a = 0.f;
#pragma unroll 8
    for (int c = 0; c < 64; ++c)
        a += part[((size_t)(b * 64 + c)) * HH + t];
    ctx_out[b * HH + t] = a * linv;
}

// ---------------------------------------------------------------------------
extern "C" void kernel_launch(void* const* d_in, const int* in_sizes, int n_in,
                              void* d_out, int out_size, void* d_ws, size_t ws_size,
                              hipStream_t stream) {
    const float* hidden = (const float*)d_in[0];
    const float* enc    = (const float*)d_in[1];
    const float* W1_w   = (const float*)d_in[2];
    const float* W1_b   = (const float*)d_in[3];
    const float* W2_w   = (const float*)d_in[4];
    const float* W2_b   = (const float*)d_in[5];
    const float* V_w    = (const float*)d_in[6];
    const float* V_b    = (const float*)d_in[7];
    (void)V_b;  // cancels in the shifted softmax

    float* out_weights = (float*)d_out;                 // B*S
    float* out_ctx     = (float*)d_out + BB * SS;       // B*H

    float* ws      = (float*)d_ws;
    float* ws_qq   = ws;                                 // 8192
    float* ws_part = ws_qq + BB * HH;                    // 524288
    float* ws_M    = ws_part + BB * 64 * HH;             // 1
    ushort* ws_w2  = (ushort*)(ws_M + 4);                // 65536 bf16

    prep_kernel<<<dim3(256 + BB + 1), dim3(256), 0, stream>>>(
        W2_w, ws_w2, hidden, W1_w, W1_b, W2_b, V_w, ws_qq, ws_M);
    score_ctx_kernel<<<dim3(8, BB), dim3(512), 0, stream>>>(
        enc, ws_w2, ws_qq, V_w, ws_M, out_weights, ws_part);
    finish_kernel<<<dim3(BB), dim3(256), 0, stream>>>(
        ws_part, out_weights, out_ctx);
}

// Round 10
// 248.796 us; speedup vs baseline: 1.2720x; 1.2720x over previous
//
#include <hip/hip_runtime.h>
#include <hip/hip_bf16.h>
#include <math.h>

#define BB 32
#define SS 4096
#define HH 256

typedef __bf16 bf16x8 __attribute__((ext_vector_type(8)));
typedef float f32x4 __attribute__((ext_vector_type(4)));

#define GLOBAL_AS __attribute__((address_space(1)))
#define LDS_AS    __attribute__((address_space(3)))

__device__ inline bf16x8 cvt8(const float4& x, const float4& y) {
    union { __hip_bfloat162 p[4]; bf16x8 v; } u;
    u.p[0] = __float22bfloat162_rn(make_float2(x.x, x.y));
    u.p[1] = __float22bfloat162_rn(make_float2(x.z, x.w));
    u.p[2] = __float22bfloat162_rn(make_float2(y.x, y.y));
    u.p[3] = __float22bfloat162_rn(make_float2(y.z, y.w));
    return u.v;
}

// tanh via exp path: ~6 VALU ops. |rel err| ~1e-7.
__device__ inline float fast_tanh(float x) {
    float xc = fminf(fmaxf(x, -10.f), 10.f);
    float e  = __expf(2.f * xc);
    return (e - 1.f) * __builtin_amdgcn_rcpf(e + 1.f);
}

// ---------------------------------------------------------------------------
// Prep (fused): blocks 0..255 swizzle W2 -> bf16 MFMA-B order;
// blocks 256..287: qq[b][h] = hidden[b]@W1[:,h] + W1_b[h] + W2_b[h];
// block 288: M = sum_h |V_w[h]| (fixed softmax shift; V_b cancels).
// w2sw[((kc*16+nt)*64+lane)*8+j] = W2[kc*32+(lane>>4)*8+j][nt*16+(lane&15)]
// ---------------------------------------------------------------------------
__global__ void prep_kernel(const float* __restrict__ W2_w,
                            ushort* __restrict__ w2sw,
                            const float* __restrict__ hidden,
                            const float* __restrict__ W1_w,
                            const float* __restrict__ W1_b,
                            const float* __restrict__ W2_b,
                            const float* __restrict__ V_w,
                            float* __restrict__ qq,
                            float* __restrict__ Mout) {
    __shared__ float red[HH];
    const int t = threadIdx.x;
    if (blockIdx.x < 256) {
        const int i = blockIdx.x * 256 + t;
        const int j    = i & 7;
        const int lane = (i >> 3) & 63;
        const int nt   = (i >> 9) & 15;
        const int kc   = i >> 13;
        const int k = kc * 32 + ((lane >> 4) & 3) * 8 + j;
        const int n = nt * 16 + (lane & 15);
        __hip_bfloat16 h = __float2bfloat16(W2_w[k * HH + n]);
        w2sw[i] = *(ushort*)&h;
    } else if (blockIdx.x < 256 + BB) {
        const int b = blockIdx.x - 256;
        red[t] = hidden[b * HH + t];
        __syncthreads();
        float acc = 0.f;
#pragma unroll 16
        for (int k = 0; k < HH; ++k)
            acc = fmaf(red[k], W1_w[k * HH + t], acc);
        qq[b * HH + t] = acc + W1_b[t] + W2_b[t];
    } else {
        red[t] = fabsf(V_w[t]);
        __syncthreads();
        for (int off = 128; off > 0; off >>= 1) {
            if (t < off) red[t] += red[t + off];
            __syncthreads();
        }
        if (t == 0) Mout[0] = red[0];
    }
}

// ---------------------------------------------------------------------------
// Fused score + partial-context. grid (64, BB), block 512 = 8 waves as
// 4(m) x 2(n); tile 64 s-rows x 256 n. Wave footprint halved vs R5:
// acc[8] f32x4 = 32 AGPR, one 16-row A-slice -> target 24 resident
// waves/CU (R2/R5/R9 establish time ~ 1/resident-waves; R5 = 12.8 waves
// at 80 us). B (W2) K-chunks double-buffered in LDS via global_load_lds;
// A at-use register loads; ctx re-reads own tile from L2.
// ---------------------------------------------------------------------------
__global__ __launch_bounds__(512, 6)
void score_ctx_kernel(const float* __restrict__ enc,
                      const ushort* __restrict__ w2sw,
                      const float* __restrict__ qq,
                      const float* __restrict__ V_w,
                      const float* __restrict__ Mptr,
                      float* __restrict__ wtilde_out,
                      float* __restrict__ part) {
    __shared__ ushort w2buf[2][8192];   // 2 x 16 KB
    __shared__ float sc_part[2][64];
    __shared__ float sc_w[64];
    __shared__ float accl2[2][HH];

    const int t    = threadIdx.x;
    const int b    = blockIdx.y;
    const int c    = blockIdx.x;
    const int s0   = c * 64;
    const int wave = t >> 6;
    const int lane = t & 63;
    const int mwi  = wave & 3;          // 16-row slice
    const int nw   = wave >> 2;         // 128-col half
    const int l15  = lane & 15;
    const int quad = lane >> 4;

    f32x4 acc[8];
#pragma unroll
    for (int nt = 0; nt < 8; ++nt) acc[nt] = (f32x4)0.f;

    // stage B chunk kc -> w2buf[bufi]: 16 KB, 512 thr x 16B x 2 sweeps
    auto stageB = [&](int kc, int bufi) {
        const char* gsrc = (const char*)w2sw + kc * 16384 + t * 16;
        char* ldst = (char*)&w2buf[bufi][0] + wave * 1024;
#pragma unroll
        for (int i = 0; i < 2; ++i)
            __builtin_amdgcn_global_load_lds(
                (const GLOBAL_AS void*)(gsrc + i * 8192),
                (LDS_AS void*)(ldst + i * 8192), 16, 0, 0);
    };

    stageB(0, 0);

    // A: row = s0 + mwi*16 + l15, k = kc*32 + quad*8 + j
    const float* aptr =
        enc + ((size_t)(b * SS + s0 + mwi * 16 + l15)) * HH + quad * 8;

    for (int kc = 0; kc < 8; ++kc) {
        __syncthreads();   // chunk kc resident (implies vmcnt drain)
        if (kc < 7) stageB(kc + 1, (kc & 1) ^ 1);
        const float4 x = *(const float4*)(aptr + kc * 32);
        const float4 y = *(const float4*)(aptr + kc * 32 + 4);
        const bf16x8 af = cvt8(x, y);
#pragma unroll
        for (int nt = 0; nt < 8; ++nt) {
            const bf16x8 bf =
                *(const bf16x8*)&w2buf[kc & 1][((nw * 8 + nt) * 64 + lane) * 8];
            acc[nt] = __builtin_amdgcn_mfma_f32_16x16x32_bf16(af, bf, acc[nt],
                                                              0, 0, 0);
        }
    }

    // Epilogue: C layout col = l15, local row (within 16) = quad*4 + r.
    const float Mv = Mptr[0];
    float p[4] = {0.f, 0.f, 0.f, 0.f};
#pragma unroll
    for (int nt = 0; nt < 8; ++nt) {
        const int n = nw * 128 + nt * 16 + l15;
        const float qn = qq[b * HH + n];
        const float vn = V_w[n];
#pragma unroll
        for (int r = 0; r < 4; ++r)
            p[r] = fmaf(vn, fast_tanh(qn + acc[nt][r]), p[r]);
    }
#pragma unroll
    for (int off = 1; off < 16; off <<= 1)
#pragma unroll
        for (int r = 0; r < 4; ++r)
            p[r] += __shfl_xor(p[r], off);

    if (l15 == 0)
        *(float4*)&sc_part[nw][mwi * 16 + quad * 4] =
            make_float4(p[0], p[1], p[2], p[3]);
    __syncthreads();
    if (t < 64) {
        const float s = sc_part[0][t] + sc_part[1][t];
        const float wt = __expf(s - Mv);
        sc_w[t] = wt;
        wtilde_out[b * SS + s0 + t] = wt;
    }
    __syncthreads();

    // ctx partial: re-read own 64 rows (L2-hot). g = row-parity, h = col.
    {
        const int g = t >> 8;       // 0/1
        const int h = t & 255;
        float a = 0.f;
        const float* ep = enc + ((size_t)(b * SS + s0)) * HH;
#pragma unroll 8
        for (int jj = 0; jj < 32; ++jj) {
            const int j = jj * 2 + g;
            a = fmaf(sc_w[j], ep[(size_t)j * HH + h], a);
        }
        accl2[g][h] = a;
    }
    __syncthreads();
    if (t < HH)
        part[((size_t)(b * 64 + c)) * HH + t] = accl2[0][t] + accl2[1][t];
}

// ---------------------------------------------------------------------------
// Finish: grid (BB), block 256. l = sum_s wtilde (read from d_out),
// weights normalized in place; ctx = (sum_c part)/l.
// ---------------------------------------------------------------------------
__global__ __launch_bounds__(256)
void finish_kernel(const float* __restrict__ part,
                   float* __restrict__ weights_out,
                   float* __restrict__ ctx_out) {
    __shared__ float red[256];
    __shared__ float linv_s;
    const int b = blockIdx.x;
    const int t = threadIdx.x;

    float4* wo4 = (float4*)(weights_out + (size_t)b * SS);
    float4 vals[4];
    float l = 0.f;
#pragma unroll
    for (int i = 0; i < 4; ++i) {
        vals[i] = wo4[i * 256 + t];
        l += vals[i].x + vals[i].y + vals[i].z + vals[i].w;
    }
    red[t] = l;
    __syncthreads();
    for (int off = 128; off > 0; off >>= 1) {
        if (t < off) red[t] += red[t + off];
        __syncthreads();
    }
    if (t == 0) linv_s = 1.f / red[0];
    __syncthreads();
    const float linv = linv_s;

#pragma unroll
    for (int i = 0; i < 4; ++i) {
        const float4 v = vals[i];
        wo4[i * 256 + t] =
            make_float4(v.x * linv, v.y * linv, v.z * linv, v.w * linv);
    }

    float a = 0.f;
#pragma unroll 8
    for (int c = 0; c < 64; ++c)
        a += part[((size_t)(b * 64 + c)) * HH + t];
    ctx_out[b * HH + t] = a * linv;
}

// ---------------------------------------------------------------------------
extern "C" void kernel_launch(void* const* d_in, const int* in_sizes, int n_in,
                              void* d_out, int out_size, void* d_ws, size_t ws_size,
                              hipStream_t stream) {
    const float* hidden = (const float*)d_in[0];
    const float* enc    = (const float*)d_in[1];
    const float* W1_w   = (const float*)d_in[2];
    const float* W1_b   = (const float*)d_in[3];
    const float* W2_w   = (const float*)d_in[4];
    const float* W2_b   = (const float*)d_in[5];
    const float* V_w    = (const float*)d_in[6];
    const float* V_b    = (const float*)d_in[7];
    (void)V_b;  // cancels in the shifted softmax

    float* out_weights = (float*)d_out;                 // B*S
    float* out_ctx     = (float*)d_out + BB * SS;       // B*H

    float* ws      = (float*)d_ws;
    float* ws_qq   = ws;                                 // 8192
    float* ws_part = ws_qq + BB * HH;                    // 524288
    float* ws_M    = ws_part + BB * 64 * HH;             // 1
    ushort* ws_w2  = (ushort*)(ws_M + 4);                // 65536 bf16

    prep_kernel<<<dim3(256 + BB + 1), dim3(256), 0, stream>>>(
        W2_w, ws_w2, hidden, W1_w, W1_b, W2_b, V_w, ws_qq, ws_M);
    score_ctx_kernel<<<dim3(64, BB), dim3(512), 0, stream>>>(
        enc, ws_w2, ws_qq, V_w, ws_M, out_weights, ws_part);
    finish_kernel<<<dim3(BB), dim3(256), 0, stream>>>(
        ws_part, out_weights, out_ctx);
}